// Round 4
// baseline (63.247 us; speedup 1.0000x reference)
//
#include <hip/hip_runtime.h>
#include <math.h>

#define INV_SQRT8 0.35355339059327373f   // (1/sqrt(2))^3

typedef __attribute__((ext_vector_type(8))) _Float16 half8;
typedef __attribute__((ext_vector_type(4))) float f32x4;

// ws layout (float offsets).  ws_size is ~512 MB (poison fills in profile); we use ~68 MB.
#define WS_S      0        // B*C*8slab*8parity = 8192 partial sums
#define WS_ATTL   8192     // B*64
#define WS_ATTH   8320     // B*448
#define WS_BIAS   9216     // 64
#define WS_SCALE  9280     // 64
#define WS_G      16384    // A-fragments: B*32768 halfs = 32768 floats
#define WS_XF     65536    // B-fragment cubes: B*64c*32768 cubes * 8 halfs = 67 MB

// ---------------- kernel 1: stream x -> parity partials + f16 cube fragments ----------------
// Block = (b, c, ds). Cube (od,oh,ow) holds the 8 taps x[2od+i][2oh+j][2ow+k], t = i*4+j*2+k.
__global__ __launch_bounds__(256, 4) void k_prep(const float* __restrict__ x,
                                                 float* __restrict__ ws) {
    int bid = blockIdx.x;                 // 1024 = b*512 + c*8 + ds
    int b = bid >> 9, c = (bid >> 3) & 63, ds = bid & 7;
    const float* xp = x + ((size_t)(b * 64 + c)) * 262144;
    _Float16* Xf = (_Float16*)(ws + WS_XF) + ((size_t)(b * 64 + c)) * 262144;
    int tid = threadIdx.x;
    float acc[2][2][2] = {};
#pragma unroll
    for (int l = 0; l < 8; ++l) {
        int p = l * 256 + tid;            // cube-pair index within slab (2048 pairs)
        int od = ds * 4 + (p >> 9), oh = (p >> 4) & 31, owp = p & 15;
        const float* src = xp + (size_t)(2 * od) * 4096 + (2 * oh) * 64 + owp * 4;
        float4 v00 = *(const float4*)(src);          // i=0 j=0, w = 4owp..4owp+3
        float4 v01 = *(const float4*)(src + 64);     // i=0 j=1
        float4 v10 = *(const float4*)(src + 4096);   // i=1 j=0
        float4 v11 = *(const float4*)(src + 4160);   // i=1 j=1
        acc[0][0][0] += v00.x + v00.z; acc[0][0][1] += v00.y + v00.w;
        acc[0][1][0] += v01.x + v01.z; acc[0][1][1] += v01.y + v01.w;
        acc[1][0][0] += v10.x + v10.z; acc[1][0][1] += v10.y + v10.w;
        acc[1][1][0] += v11.x + v11.z; acc[1][1][1] += v11.y + v11.w;
        half8 cA, cB;                                 // cubes ow = 2owp, 2owp+1
        cA[0]=(_Float16)v00.x; cA[1]=(_Float16)v00.y; cA[2]=(_Float16)v01.x; cA[3]=(_Float16)v01.y;
        cA[4]=(_Float16)v10.x; cA[5]=(_Float16)v10.y; cA[6]=(_Float16)v11.x; cA[7]=(_Float16)v11.y;
        cB[0]=(_Float16)v00.z; cB[1]=(_Float16)v00.w; cB[2]=(_Float16)v01.z; cB[3]=(_Float16)v01.w;
        cB[4]=(_Float16)v10.z; cB[5]=(_Float16)v10.w; cB[6]=(_Float16)v11.z; cB[7]=(_Float16)v11.w;
        size_t cidx = (size_t)od * 1024 + oh * 32 + owp * 2;
        *(half8*)(Xf + cidx * 8)     = cA;
        *(half8*)(Xf + cidx * 8 + 8) = cB;
    }
    float a[8];
#pragma unroll
    for (int r = 0; r < 8; ++r) a[r] = acc[(r >> 2) & 1][(r >> 1) & 1][r & 1];
#pragma unroll
    for (int off = 1; off < 64; off <<= 1)
#pragma unroll
        for (int r = 0; r < 8; ++r) a[r] += __shfl_xor(a[r], off);
    __shared__ float red[4][8];
    int wave = tid >> 6, lane = tid & 63;
    if (lane == 0)
        for (int r = 0; r < 8; ++r) red[wave][r] = a[r];
    __syncthreads();
    if (tid < 8) {
        float v = red[0][tid] + red[1][tid] + red[2][tid] + red[3][tid];
        ws[WS_S + ((b * 64 + c) * 8 + ds) * 8 + tid] = v;
    }
}

// ---------------- kernel 2: subband means -> attention MLPs -> att/scale/bias ----------------
__global__ __launch_bounds__(512) void k_att(const float* __restrict__ lw1,
    const float* __restrict__ lw2, const float* __restrict__ hw1,
    const float* __restrict__ hw2, const float* __restrict__ fuse_b,
    const float* __restrict__ gamma, const float* __restrict__ beta,
    const float* __restrict__ mean, const float* __restrict__ var,
    float* __restrict__ ws) {
    int b = blockIdx.x, tid = threadIdx.x;
    const float* Sin = ws + WS_S;
    __shared__ float ml[64], mh[448], hidL[4], hidH[28];
    const float KN = INV_SQRT8 / 32768.0f;
    if (tid < 64) {
        float s8[8];
#pragma unroll
        for (int r = 0; r < 8; ++r) s8[r] = 0.f;
        for (int ds = 0; ds < 8; ++ds)
#pragma unroll
            for (int r = 0; r < 8; ++r)
                s8[r] += Sin[((b * 64 + tid) * 8 + ds) * 8 + r];
        float tot = 0;
#pragma unroll
        for (int r = 0; r < 8; ++r) tot += s8[r];
        ml[tid] = tot * KN;
        for (int pq = 1; pq < 8; ++pq) {   // subband code pqr = s'+1
            float v = 0;
#pragma unroll
            for (int r = 0; r < 8; ++r) v += (__popc(pq & r) & 1) ? -s8[r] : s8[r];
            mh[tid * 7 + pq - 1] = v * KN;
        }
    }
    __syncthreads();
    if (tid < 4) {
        float v = 0;
        for (int c = 0; c < 64; ++c) v += ml[c] * lw1[tid * 64 + c];
        hidL[tid] = fmaxf(v, 0.f);
    } else if (tid >= 64 && tid < 92) {
        int hh = tid - 64;
        float v = 0;
        for (int k = 0; k < 448; ++k) v += mh[k] * hw1[hh * 448 + k];
        hidH[hh] = fmaxf(v, 0.f);
    }
    __syncthreads();
    if (tid < 64) {
        float v = 0;
#pragma unroll
        for (int hh = 0; hh < 4; ++hh) v += hidL[hh] * lw2[tid * 4 + hh];
        ws[WS_ATTL + b * 64 + tid] = 1.f / (1.f + expf(-v));
    } else if (tid - 64 < 448) {
        int hc = tid - 64;
        float v = 0;
#pragma unroll
        for (int hh = 0; hh < 28; ++hh) v += hidH[hh] * hw2[hc * 28 + hh];
        ws[WS_ATTH + b * 448 + hc] = 1.f / (1.f + expf(-v));
    }
    if (b == 0 && tid < 64) {
        float sc = gamma[tid] * rsqrtf(var[tid] + 1e-5f);
        ws[WS_SCALE + tid] = sc;
        ws[WS_BIAS + tid] = sc * (fuse_b[tid] - mean[tid]) + beta[tid];
    }
}

// ---------------- kernel 3: conv weights as f16 MFMA A-fragments ----------------
// frag f = (c>>2)*4 + (o>>4); lane = (c&3)*16 + (o&15); elem = tap t.
__global__ __launch_bounds__(64) void k_weights(const float* __restrict__ fuse_w,
                                                float* __restrict__ ws) {
    int b = blockIdx.x >> 6, o = blockIdx.x & 63, c = threadIdx.x;
    const float* attL = ws + WS_ATTL + b * 64;
    const float* attH = ws + WS_ATTH + b * 448;
    float W[8];
    W[0] = fuse_w[o * 512 + c] * attL[c];
#pragma unroll
    for (int s = 1; s < 8; ++s)
        W[s] = fuse_w[o * 512 + 64 + c * 7 + (s - 1)] * attH[c * 7 + s - 1];
    float sc = ws[WS_SCALE + o] * INV_SQRT8;
    half8 hv;
#pragma unroll
    for (int t = 0; t < 8; ++t) {
        float g = 0;
#pragma unroll
        for (int s = 0; s < 8; ++s) g += (__popc(s & t) & 1) ? -W[s] : W[s];
        hv[t] = (_Float16)(g * sc);
    }
    _Float16* Gf = (_Float16*)(ws + WS_G);
    size_t idx = (size_t)b * 32768 +
                 ((((size_t)(c >> 2) * 4 + (o >> 4)) * 64) + (c & 3) * 16 + (o & 15)) * 8;
    *(half8*)(Gf + idx) = hv;
}

// ---------------- kernel 4: conv via MFMA, fragments straight from global ----------------
// Block: (b, d, h0 = 2 rows) -> 64o x 64n. 4 waves; wave wv owns n-chunk 16.
// No LDS, no barriers: 80 x 16B loads + 64 MFMAs per wave.
__global__ __launch_bounds__(256, 4) void k_conv(const float* __restrict__ ws_c,
                                                 float* __restrict__ out) {
    const float* ws = ws_c;
    int blk = blockIdx.x;                 // 1024 = b*512 + d*16 + ht
    int b = blk >> 9, d = (blk >> 4) & 31, h0 = (blk & 15) * 2;
    int tid = threadIdx.x, lane = tid & 63, wv = tid >> 6;
    int g = lane >> 4;
    int oh = h0 + (wv >> 1), ow = (wv & 1) * 16 + (lane & 15);
    const _Float16* Gf = (const _Float16*)(ws + WS_G) + (size_t)b * 32768;
    const _Float16* xlane = (const _Float16*)(ws + WS_XF)
        + (size_t)(b * 64 + g) * 262144
        + ((size_t)d * 1024 + oh * 32 + ow) * 8;
    f32x4 acc[4] = {};
#pragma unroll
    for (int ch = 0; ch < 4; ++ch) {
#pragma unroll
        for (int ks = 0; ks < 4; ++ks) {
            half8 bfrag = *(const half8*)(xlane + (size_t)(ch * 16 + ks * 4) * 262144);
            const _Float16* ga = Gf + (size_t)((ch * 4 + ks) * 4) * 512 + lane * 8;
#pragma unroll
            for (int ot = 0; ot < 4; ++ot) {
                half8 afrag = *(const half8*)(ga + ot * 512);
                acc[ot] = __builtin_amdgcn_mfma_f32_16x16x32_f16(afrag, bfrag, acc[ot], 0, 0, 0);
            }
        }
    }
    // epilogue: D layout n=lane&15, m=g*4+r
    float* ob = out + ((((size_t)b * 64) * 32 + d) * 32 + oh) * 32 + ow;
#pragma unroll
    for (int ot = 0; ot < 4; ++ot)
#pragma unroll
        for (int r = 0; r < 4; ++r) {
            int o = ot * 16 + g * 4 + r;
            float v = acc[ot][r] + ws[WS_BIAS + o];
            ob[(size_t)o * 32768] = fmaxf(v, 0.f);
        }
}

extern "C" void kernel_launch(void* const* d_in, const int* in_sizes, int n_in,
                              void* d_out, int out_size, void* d_ws, size_t ws_size,
                              hipStream_t stream) {
    const float* x      = (const float*)d_in[0];
    const float* lw1    = (const float*)d_in[1];
    const float* lw2    = (const float*)d_in[2];
    const float* hw1    = (const float*)d_in[3];
    const float* hw2    = (const float*)d_in[4];
    const float* fuse_w = (const float*)d_in[5];
    const float* fuse_b = (const float*)d_in[6];
    const float* gamma  = (const float*)d_in[7];
    const float* beta   = (const float*)d_in[8];
    const float* mean   = (const float*)d_in[9];
    const float* var    = (const float*)d_in[10];
    float* ws  = (float*)d_ws;
    float* out = (float*)d_out;

    k_prep<<<2 * 64 * 8, 256, 0, stream>>>(x, ws);
    k_att<<<2, 512, 0, stream>>>(lw1, lw2, hw1, hw2,
                                 fuse_b, gamma, beta, mean, var, ws);
    k_weights<<<2 * 64, 64, 0, stream>>>(fuse_w, ws);
    k_conv<<<2 * 32 * 16, 256, 0, stream>>>(ws, out);
}